// Round 16
// baseline (48.302 us; speedup 1.0000x reference)
//
#include <hip/hip_runtime.h>

// CategoryDense: out[b,c,o] = sum_i x[b,c,i] * kernel[c,i,o] + bias[c,o]
// B=8192, C=64, IN=64, OUT=64, fp32 in/out. bf16 MFMA (swapped operands).
//
// R16 = R15 with the kb gather moved from L2 to LDS:
//  - k[c] staged once -> 8KB bf16 LDS (coalesced), kb built via ds_read
//    gathers (256B-strided lane pattern = ~2-way bank alias, free) instead
//    of 64x 64-line L2 gather transactions per wave (R15's hidden cost).
//  - x B-frags direct global->reg (R4/R11 proven FETCH=66MB)
//  - epilogue: per-wave LDS repack -> full-line (4 rows x 256B) nontemporal
//    stores (R12 proven: WRITE=131MB, preserves x in L3 across replays)
//  - BT=256, 4 waves, grid=2048, launch_bounds(256,4); LDS 40KB.

constexpr int C_   = 64;
constexpr int IN_  = 64;
constexpr int OUT_ = 64;
constexpr int BT   = 256;

typedef __attribute__((ext_vector_type(8))) short bf16x8;
typedef __attribute__((ext_vector_type(4))) short s16x4;
typedef __attribute__((ext_vector_type(4))) float f32x4;

__device__ __forceinline__ short f2bf(float f) {
    union { float f; unsigned u; } v; v.f = f;
    unsigned r = v.u + 0x7FFF + ((v.u >> 16) & 1);   // RNE
    return (short)(r >> 16);
}

__device__ __forceinline__ bf16x8 cvt8(f32x4 lo, f32x4 hi) {
    bf16x8 r;
    #pragma unroll
    for (int e = 0; e < 4; ++e) {
        r[e]     = f2bf(lo[e]);
        r[4 + e] = f2bf(hi[e]);
    }
    return r;
}

__global__ __launch_bounds__(256, 4)
void cat_dense_mfma12(const float* __restrict__ x,
                      const float* __restrict__ k,
                      const float* __restrict__ bias,
                      float* __restrict__ out) {
    __shared__ float rp[4][32 * 64];            // 32 KB: per-wave repack
    __shared__ unsigned short ksb[IN_ * OUT_];  //  8 KB: bf16 k[c] [i][o]

    const int tid  = threadIdx.x;
    const int wv   = tid >> 6;
    const int lane = tid & 63;
    const int c    = blockIdx.x & 63;
    const long bBase = (long)(blockIdx.x >> 6) * BT;

    const int lrow = lane & 15;   // B col = batch row; A row = out channel
    const int lkg  = lane >> 4;   // K-octet select; C row-group

    // ---- stage k[c] -> bf16 LDS (linear, coalesced) ----
    #pragma unroll
    for (int it = 0; it < 4; ++it) {
        int p = tid + it * 256;
        f32x4 v = *(const f32x4*)(k + (size_t)c * (IN_ * OUT_) + (size_t)p * 4);
        s16x4 w;
        #pragma unroll
        for (int e = 0; e < 4; ++e) w[e] = f2bf(v[e]);
        *(s16x4*)(&ksb[p * 4]) = w;
    }

    // ---- xT B-fragments direct from global (issued before the barrier) ----
    const long rw = bBase + wv * 64;
    bf16x8 af[2][2][2];   // [p][mt][ksi]
    #pragma unroll
    for (int p = 0; p < 2; ++p)
      #pragma unroll
      for (int mt = 0; mt < 2; ++mt)
        #pragma unroll
        for (int ksi = 0; ksi < 2; ++ksi) {
            const float* xp = x
                + (size_t)(rw + p * 32 + mt * 16 + lrow) * (C_ * IN_)
                + (size_t)c * IN_ + ksi * 32 + lkg * 8;
            f32x4 lo = *(const f32x4*)xp;
            f32x4 hi = *(const f32x4*)(xp + 4);
            af[p][mt][ksi] = cvt8(lo, hi);
        }

    // bias: lane's 4 consecutive output cols per nt (o = nt*16 + lkg*4 ..+4)
    f32x4 bv[4];
    #pragma unroll
    for (int nt = 0; nt < 4; ++nt)
        bv[nt] = *(const f32x4*)(bias + (size_t)c * OUT_ + nt * 16 + lkg * 4);

    __syncthreads();   // k staged

    // ---- kT A-fragments from LDS (strided gather, ~2-way alias = free) ----
    // A[row=o=nt*16+lrow][k=i=ksi*32+lkg*8+j] = ksb[i*64 + o]
    bf16x8 kb[4][2];
    #pragma unroll
    for (int nt = 0; nt < 4; ++nt)
      #pragma unroll
      for (int ksi = 0; ksi < 2; ++ksi) {
        union { bf16x8 v; short s[8]; } b;
        #pragma unroll
        for (int j = 0; j < 8; ++j)
            b.s[j] = (short)ksb[(ksi * 32 + lkg * 8 + j) * OUT_ + nt * 16 + lrow];
        kb[nt][ksi] = b.v;
      }

    float* rpw = &rp[wv][0];

    // ---- two M=32 passes: MFMA -> LDS repack -> full-line nt stores ----
    #pragma unroll
    for (int p = 0; p < 2; ++p) {
        f32x4 acc[2][4];
        #pragma unroll
        for (int mt = 0; mt < 2; ++mt)
          #pragma unroll
          for (int nt = 0; nt < 4; ++nt)
            acc[mt][nt] = (f32x4){0.f, 0.f, 0.f, 0.f};

        #pragma unroll
        for (int ksi = 0; ksi < 2; ++ksi)
          #pragma unroll
          for (int mt = 0; mt < 2; ++mt)
            #pragma unroll
            for (int nt = 0; nt < 4; ++nt)
                acc[mt][nt] = __builtin_amdgcn_mfma_f32_16x16x32_bf16(
                                  kb[nt][ksi], af[p][mt][ksi],
                                  acc[mt][nt], 0, 0, 0);

        // acc(+bias) -> LDS, XOR-swizzled within each 64-word row
        #pragma unroll
        for (int mt = 0; mt < 2; ++mt) {
            int bl = mt * 16 + lrow;
            #pragma unroll
            for (int nt = 0; nt < 4; ++nt) {
                int off = ((nt * 16 + lkg * 4) ^ (lrow << 2));
                *(f32x4*)(&rpw[bl * 64 + off]) = acc[mt][nt] + bv[nt];
            }
        }

        // read back (matching unswizzle): instr j covers 4 rows x 256B full
        // lines -> nontemporal store (evict-first, no partial-line writeback)
        const int m = lane & 15;    // 16B chunk within row
        const int t = lane >> 4;    // row within group of 4
        #pragma unroll
        for (int j = 0; j < 8; ++j) {
            int bl   = j * 4 + t;
            int offr = (m << 2) ^ ((bl & 15) << 2);
            f32x4 v = *(const f32x4*)(&rpw[bl * 64 + offr]);
            size_t ob = (size_t)(rw + p * 32 + bl) * (C_ * OUT_)
                      + (size_t)c * OUT_ + m * 4;
            __builtin_nontemporal_store(v, (f32x4*)(out + ob));
        }
    }
}

extern "C" void kernel_launch(void* const* d_in, const int* in_sizes, int n_in,
                              void* d_out, int out_size, void* d_ws, size_t ws_size,
                              hipStream_t stream) {
    const float* x    = (const float*)d_in[0];
    const float* k    = (const float*)d_in[1];
    const float* bias = (const float*)d_in[2];
    float* out        = (float*)d_out;

    const int B     = in_sizes[0] / (C_ * IN_);   // 8192
    const int tiles = B / BT;                     // 32
    dim3 grid(64 * tiles);                        // 2048: c = blk & 63
    cat_dense_mfma12<<<grid, 256, 0, stream>>>(x, k, bias, out);
}

// Round 17
// 46.676 us; speedup vs baseline: 1.0348x; 1.0348x over previous
//
#include <hip/hip_runtime.h>

// CategoryDense: out[b,c,o] = sum_i x[b,c,i] * kernel[c,i,o] + bias[c,o]
// B=8192, C=64, IN=64, OUT=64, fp32 in/out. bf16 MFMA (swapped operands).
//
// FINAL (= R15, the measured best at 46.7us, ideal traffic 66+131MB):
//  - kT A-fragments built directly from original k[c][i][o] via 64 scalar
//    dword loads + cvt per thread (k[c]=16KB L2-resident; hidden under x)
//  - x B-frags direct global->reg (FETCH=66MB proven)
//  - epilogue: per-wave LDS repack -> full-line (4 rows x 256B) nontemporal
//    stores (WRITE=131MB proven, no partial-line writeback)
//  - BT=256, 4 waves, grid=2048, launch_bounds(256,4) (R9/R13 lesson:
//    never cap below the unified VGPR+AGPR live set)
// Falsified alternatives: LDS-staged k (R16 +1.6us), occupancy push
// (R13/R14 spill/overhead), BT=512 (R8 traffic amplification), plain
// scattered stores (R12 epilogue is -8.7us vs R11).

constexpr int C_   = 64;
constexpr int IN_  = 64;
constexpr int OUT_ = 64;
constexpr int BT   = 256;

typedef __attribute__((ext_vector_type(8))) short bf16x8;
typedef __attribute__((ext_vector_type(4))) float f32x4;

__device__ __forceinline__ short f2bf(float f) {
    union { float f; unsigned u; } v; v.f = f;
    unsigned r = v.u + 0x7FFF + ((v.u >> 16) & 1);   // RNE
    return (short)(r >> 16);
}

__device__ __forceinline__ bf16x8 cvt8(f32x4 lo, f32x4 hi) {
    bf16x8 r;
    #pragma unroll
    for (int e = 0; e < 4; ++e) {
        r[e]     = f2bf(lo[e]);
        r[4 + e] = f2bf(hi[e]);
    }
    return r;
}

__global__ __launch_bounds__(256, 4)
void cat_dense_mfma11(const float* __restrict__ x,
                      const float* __restrict__ k,
                      const float* __restrict__ bias,
                      float* __restrict__ out) {
    __shared__ float rp[4][32 * 64];   // 32 KB: per-wave 8 KB repack buffer

    const int tid  = threadIdx.x;
    const int wv   = tid >> 6;
    const int lane = tid & 63;
    const int c    = blockIdx.x & 63;
    const long bBase = (long)(blockIdx.x >> 6) * BT;

    const int lrow = lane & 15;   // B col = batch row; A row = out channel
    const int lkg  = lane >> 4;   // K-octet select; C row-group

    // ---- xT B-fragments direct from global (HBM latency — issue first) ----
    const long rw = bBase + wv * 64;
    bf16x8 af[2][2][2];   // [p][mt][ksi]
    #pragma unroll
    for (int p = 0; p < 2; ++p)
      #pragma unroll
      for (int mt = 0; mt < 2; ++mt)
        #pragma unroll
        for (int ksi = 0; ksi < 2; ++ksi) {
            const float* xp = x
                + (size_t)(rw + p * 32 + mt * 16 + lrow) * (C_ * IN_)
                + (size_t)c * IN_ + ksi * 32 + lkg * 8;
            f32x4 lo = *(const f32x4*)xp;
            f32x4 hi = *(const f32x4*)(xp + 4);
            af[p][mt][ksi] = cvt8(lo, hi);
        }

    // ---- kT A-fragments direct from original k layout (L2-resident) ----
    // A[row=o=nt*16+lrow][k=i=ksi*32+lkg*8+j] = k[c][i][o]
    const float* kc = k + (size_t)c * (IN_ * OUT_);
    bf16x8 kb[4][2];
    #pragma unroll
    for (int nt = 0; nt < 4; ++nt)
      #pragma unroll
      for (int ksi = 0; ksi < 2; ++ksi) {
        union { bf16x8 v; short s[8]; } b;
        #pragma unroll
        for (int j = 0; j < 8; ++j)
            b.s[j] = f2bf(kc[(ksi * 32 + lkg * 8 + j) * OUT_ + nt * 16 + lrow]);
        kb[nt][ksi] = b.v;
      }

    // bias: lane's 4 consecutive output cols per nt (o = nt*16 + lkg*4 ..+4)
    f32x4 bv[4];
    #pragma unroll
    for (int nt = 0; nt < 4; ++nt)
        bv[nt] = *(const f32x4*)(bias + (size_t)c * OUT_ + nt * 16 + lkg * 4);

    float* rpw = &rp[wv][0];

    // ---- two M=32 passes: MFMA -> LDS repack -> full-line nt stores ----
    #pragma unroll
    for (int p = 0; p < 2; ++p) {
        f32x4 acc[2][4];
        #pragma unroll
        for (int mt = 0; mt < 2; ++mt)
          #pragma unroll
          for (int nt = 0; nt < 4; ++nt)
            acc[mt][nt] = (f32x4){0.f, 0.f, 0.f, 0.f};

        #pragma unroll
        for (int ksi = 0; ksi < 2; ++ksi)
          #pragma unroll
          for (int mt = 0; mt < 2; ++mt)
            #pragma unroll
            for (int nt = 0; nt < 4; ++nt)
                acc[mt][nt] = __builtin_amdgcn_mfma_f32_16x16x32_bf16(
                                  kb[nt][ksi], af[p][mt][ksi],
                                  acc[mt][nt], 0, 0, 0);

        // acc(+bias) -> LDS, XOR-swizzled within each 64-word row
        #pragma unroll
        for (int mt = 0; mt < 2; ++mt) {
            int bl = mt * 16 + lrow;
            #pragma unroll
            for (int nt = 0; nt < 4; ++nt) {
                int off = ((nt * 16 + lkg * 4) ^ (lrow << 2));
                *(f32x4*)(&rpw[bl * 64 + off]) = acc[mt][nt] + bv[nt];
            }
        }

        // read back (matching unswizzle): instr j covers 4 rows x 256B full
        // lines -> nontemporal store (evict-first, no partial-line writeback)
        const int m = lane & 15;    // 16B chunk within row
        const int t = lane >> 4;    // row within group of 4
        #pragma unroll
        for (int j = 0; j < 8; ++j) {
            int bl   = j * 4 + t;
            int offr = (m << 2) ^ ((bl & 15) << 2);
            f32x4 v = *(const f32x4*)(&rpw[bl * 64 + offr]);
            size_t ob = (size_t)(rw + p * 32 + bl) * (C_ * OUT_)
                      + (size_t)c * OUT_ + m * 4;
            __builtin_nontemporal_store(v, (f32x4*)(out + ob));
        }
    }
}

extern "C" void kernel_launch(void* const* d_in, const int* in_sizes, int n_in,
                              void* d_out, int out_size, void* d_ws, size_t ws_size,
                              hipStream_t stream) {
    const float* x    = (const float*)d_in[0];
    const float* k    = (const float*)d_in[1];
    const float* bias = (const float*)d_in[2];
    float* out        = (float*)d_out;

    const int B     = in_sizes[0] / (C_ * IN_);   // 8192
    const int tiles = B / BT;                     // 32
    dim3 grid(64 * tiles);                        // 2048: c = blk & 63
    cat_dense_mfma11<<<grid, 256, 0, stream>>>(x, k, bias, out);
}